// Round 2
// baseline (211.735 us; speedup 1.0000x reference)
//
#include <hip/hip_runtime.h>

// NodeClassifier 3-layer MP-GNN, MI355X. R8b: resubmit of R8 (infra failure,
// no verdict). Theory: gather is latency-bound (164MB/layer from L2/L3,
// ~900cy misses, only ~2.4 blocks/CU TLP, and the old loop vmcnt(0)-drained
// every 8-load batch).
// Fixes: (a) uint4 gather loads = 2 edges/instr (8KB/wave in flight, half the
// instrs), halves combined at flush via shfl_xor(32); (b) flat 2-deep batch
// pipeline across the wave's 4 nodes (issue b+1 while summing b -> counted
// vmcnt, no drains, no inter-node bubble); (c) W k-step register prefetch
// (k0=0 issued before gather, k0+32 during MFMAs); (d) agg40: 6 edges/instr
// (10 lanes x 4 cols), 48-edge batches, 3-round shuffle fold, float4 stores.
// Structure: 5 dispatches (prep, place, L1 fused, L2 fused + chained L3, agg40).
// agg(x@W+b) == agg(x)@W + deg*b. Lessons: grid.sync ~35us (R3); serial
// single-block work = straggler (R4); tile-shape tweaks alone ~neutral (R7).

#define N_NODES   10000
#define N_EDGES   320000
#define D_HID     256
#define N_CLASSES 40
#define CAP       96

typedef __attribute__((ext_vector_type(8))) short short8;
typedef __attribute__((ext_vector_type(4))) float f32x4;

__device__ __forceinline__ ushort f2bf(float f) {
    unsigned u = __float_as_uint(f);
    u = (u + 0x7fffu + ((u >> 16) & 1u)) >> 16;   // RNE; inputs finite
    return (ushort)u;
}
__device__ __forceinline__ float bf2f(ushort u) {
    return __uint_as_float(((unsigned)u) << 16);
}

// ---------------- prep: zero cursor, fill esrc with dummy, pad rows, bf16 conv ----------------

__global__ __launch_bounds__(256)
void prep_kernel(const float* __restrict__ X,
                 const float* __restrict__ W1, const float* __restrict__ W2,
                 const float* __restrict__ W3,
                 ushort* __restrict__ Xb, ushort* __restrict__ bufY,
                 ushort* __restrict__ bufH,
                 ushort* __restrict__ W1b, ushort* __restrict__ W2b,
                 ushort* __restrict__ W3b, int* __restrict__ cursor,
                 int* __restrict__ esrc) {
    const int tid  = blockIdx.x * 256 + threadIdx.x;
    const int nthr = gridDim.x * 256;
    for (int i = tid; i < N_NODES; i += nthr) cursor[i] = 0;
    // dummy-fill all bucket slots with padding node 10000 (zero row)
    for (int i = tid; i < N_NODES * CAP; i += nthr) esrc[i] = N_NODES;
    // zero the padding rows
    ushort4 z; z.x = 0; z.y = 0; z.z = 0; z.w = 0;
    if (tid < 64) {
        ((ushort4*)Xb)[640000 + tid]   = z;   // row 10000 of Xb
        ((ushort4*)bufY)[640000 + tid] = z;   // row 10000 of bufY
    }
    if (tid < 10) ((ushort4*)bufH)[100000 + tid] = z;  // row 10000 of bufH
    // X -> bf16
    for (int i = tid; i < N_NODES * D_HID / 4; i += nthr) {
        float4 v = ((const float4*)X)[i];
        ushort4 o;
        o.x = f2bf(v.x); o.y = f2bf(v.y); o.z = f2bf(v.z); o.w = f2bf(v.w);
        ((ushort4*)Xb)[i] = o;
    }
    // weights -> bf16, transposed to n-major
    for (int i = tid; i < 141312; i += nthr) {
        if (i < 65536) {
            int n = i >> 8, k = i & 255;
            W1b[i] = f2bf(W1[k * 256 + n]);
        } else if (i < 131072) {
            int t2 = i - 65536;
            int n = t2 >> 8, k = t2 & 255;
            W2b[t2] = f2bf(W2[k * 256 + n]);
        } else {
            int t2 = i - 131072;
            int n = t2 >> 8, k = t2 & 255;
            W3b[t2] = f2bf(W3[k * N_CLASSES + n]);
        }
    }
}

// ---------------- place: bucket CSR via global atomics ----------------

__global__ __launch_bounds__(256)
void place_kernel(const int* __restrict__ edges, int* __restrict__ cursor,
                  int* __restrict__ esrc) {
    int e = blockIdx.x * 256 + threadIdx.x;
    if (e < N_EDGES) {
        int d = edges[N_EDGES + e];
        int pos = atomicAdd(&cursor[d], 1);
        if (pos < CAP) esrc[d * CAP + pos] = edges[e];
    }
}

// ---------------- fused layer: agg(16 nodes) -> LDS -> MFMA GEMM -> relu ----------------
// Block: 16 nodes x 256 cols, 256 threads (4 waves), 625 blocks (10000/16 exact).
// Phase 0: stage 16x96 edge indices + degrees into LDS (coalesced).
// Phase 1: wave-per-node gather, 4 nodes/wave. uint4 loads = 2 edges/instr,
//          batch = 16 edges, 2-deep flat pipeline across the wave's 4 nodes,
//          halves combined at flush via shfl_xor(32).
// Phase 2: GEMM 16x256 @ 256x256; wave w covers cols w*64..+64 (4 MFMA/k-step);
//          W k-step staged via register prefetch (k0=0 issued before gather).
// CHAIN: out2 tile stays in LDS -> @W3 + b3 -> h3 global (wave<3 does 16 cols each).

#define LDSA 264   // padded LDS row stride (bf16): 132 dwords % 32 banks = 4 -> benign

template<bool CHAIN>
__global__ __launch_bounds__(256)
void layer_kernel(const ushort* __restrict__ Xin, const ushort* __restrict__ Bt,
                  const float* __restrict__ bias,
                  const int* __restrict__ deg, const int* __restrict__ esrc,
                  const ushort* __restrict__ W3b, const float* __restrict__ b3,
                  ushort* __restrict__ Out) {
    __shared__ ushort As[16 * LDSA];      // 8448 B; x_agg, reused as out2 when CHAIN
    __shared__ ushort Bs[40 * LDSA];      // 21120 B; main: [256 n][40-stride 32k]; chain: W3
    __shared__ int    eidxL[16 * CAP];    // 6144 B
    __shared__ int    degI[16];
    __shared__ float  degF[16];

    const int tid = threadIdx.x;
    const int wave = tid >> 6, lane = tid & 63;
    const int lr = lane & 15, lg = lane >> 4;
    const int lo = lane & 31, hi = lane >> 5;
    const int rowBase = blockIdx.x * 16;

    // ---- phase 0: stage edge lists + degrees ----
#pragma unroll
    for (int p = 0; p < 6; ++p) {
        int idx = p * 256 + tid;          // 0..1535
        eidxL[idx] = esrc[rowBase * CAP + idx];
    }
    if (tid < 16) {
        int c = deg[rowBase + tid];
        degF[tid] = (float)c;             // true degree (bias term)
        degI[tid] = (c > CAP) ? CAP : c;
    }
    __syncthreads();

    // ---- issue W tile for k0=0 now: its L2 latency hides under the gather ----
    uint4 wreg[4];
    auto loadW = [&](int k0) {
#pragma unroll
        for (int p = 0; p < 4; ++p) {
            int idx = p * 256 + tid;      // 1024 x 16B chunks
            int n = idx >> 2, c = (idx & 3) * 8;
            wreg[p] = *(const uint4*)(Bt + (size_t)n * 256 + k0 + c);
        }
    };
    loadW(0);

    // ---- phase 1: gather, flat 2-deep pipelined batches of 16 edges ----
    const uint4* hp4 = (const uint4*)Xin;

    // per-node batch counts (batches of 16 edges, dummy-padded; esrc prefilled)
    unsigned bpack = 0; int total = 0;
#pragma unroll
    for (int it = 0; it < 4; ++it) {
        int nb = (degI[wave * 4 + it] + 15) >> 4;   // 0..6
        bpack |= (unsigned)nb << (8 * it);
        total += nb;
    }
    // zero-degree nodes: write their As row now (rare)
#pragma unroll
    for (int it = 0; it < 4; ++it) {
        if (((bpack >> (8 * it)) & 255u) == 0u && lane < 32) {
            uint4 z{};
            *((uint4*)(As + (wave * 4 + it) * LDSA) + lane) = z;
        }
    }

    int issIt = 0;
    while (issIt < 4 && ((bpack >> (8 * issIt)) & 255u) == 0u) ++issIt;
    int issRem = (issIt < 4) ? (int)((bpack >> (8 * issIt)) & 255u) : 0;
    int issOff = 0;
    int conIt = issIt, conRem = issRem;

    uint4 vA[8], vB[8];
    float a[8] = {};

    auto ISSUE = [&](uint4* v) {
        int ibase = (wave * 4 + issIt) * CAP + issOff;
#pragma unroll
        for (int u = 0; u < 8; ++u) {
            int e = eidxL[ibase + 2 * u + hi];      // lanes 0-31: edge 2u, 32-63: 2u+1
            v[u] = hp4[(size_t)e * 32 + lo];        // 16B/lane, 2 full rows/instr
        }
        issOff += 16;
        if (--issRem == 0) {
            do { ++issIt; } while (issIt < 4 && ((bpack >> (8 * issIt)) & 255u) == 0u);
            issRem = (issIt < 4) ? (int)((bpack >> (8 * issIt)) & 255u) : 0;
            issOff = 0;
        }
    };
    auto FLUSH = [&]() {
#pragma unroll
        for (int j = 0; j < 8; ++j) a[j] += __shfl_xor(a[j], 32);
        if (lane < 32) {
            uint4 o;
            o.x = (unsigned)f2bf(a[0]) | ((unsigned)f2bf(a[1]) << 16);
            o.y = (unsigned)f2bf(a[2]) | ((unsigned)f2bf(a[3]) << 16);
            o.z = (unsigned)f2bf(a[4]) | ((unsigned)f2bf(a[5]) << 16);
            o.w = (unsigned)f2bf(a[6]) | ((unsigned)f2bf(a[7]) << 16);
            *((uint4*)(As + (wave * 4 + conIt) * LDSA) + lane) = o;
        }
#pragma unroll
        for (int j = 0; j < 8; ++j) a[j] = 0.f;
    };
    auto CONSUME = [&](uint4* v) {
#pragma unroll
        for (int u = 0; u < 8; ++u) {
            a[0] += bf2f((ushort)(v[u].x & 0xffff)); a[1] += bf2f((ushort)(v[u].x >> 16));
            a[2] += bf2f((ushort)(v[u].y & 0xffff)); a[3] += bf2f((ushort)(v[u].y >> 16));
            a[4] += bf2f((ushort)(v[u].z & 0xffff)); a[5] += bf2f((ushort)(v[u].z >> 16));
            a[6] += bf2f((ushort)(v[u].w & 0xffff)); a[7] += bf2f((ushort)(v[u].w >> 16));
        }
        if (--conRem == 0) {
            FLUSH();
            do { ++conIt; } while (conIt < 4 && ((bpack >> (8 * conIt)) & 255u) == 0u);
            conRem = (conIt < 4) ? (int)((bpack >> (8 * conIt)) & 255u) : 0;
        }
    };

    if (total > 0) {
        ISSUE(vA);
        int done = 0;
#pragma unroll 1
        while (true) {
            if (done + 1 < total) ISSUE(vB);   // issue b+1 while summing b
            CONSUME(vA);
            if (++done >= total) break;
            if (done + 1 < total) ISSUE(vA);
            CONSUME(vB);
            if (++done >= total) break;
        }
    }

    // ---- phase 2: GEMM 16x256 @ 256x256, W via register prefetch ----
    f32x4 acc[4] = {};
    for (int k0 = 0; k0 < 256; k0 += 32) {
        __syncthreads();                   // As ready (k0=0) / Bs reads done (k0>0)
#pragma unroll
        for (int p = 0; p < 4; ++p) {
            int idx = p * 256 + tid;
            int n = idx >> 2, c = (idx & 3) * 8;
            *(uint4*)(Bs + n * 40 + c) = wreg[p];
        }
        __syncthreads();
        if (k0 + 32 < 256) loadW(k0 + 32); // prefetch next W chunk under the MFMAs
        short8 af = *(const short8*)(As + lr * LDSA + k0 + lg * 8);
#pragma unroll
        for (int j = 0; j < 4; ++j) {
            short8 bf = *(const short8*)(Bs + (wave * 64 + j * 16 + lr) * 40 + lg * 8);
            acc[j] = __builtin_amdgcn_mfma_f32_16x16x32_bf16(af, bf, acc[j], 0, 0, 0);
        }
    }

    if (!CHAIN) {
        // epilogue: relu(acc + deg*b) -> bf16 global (all rows exist: 625*16=10000)
#pragma unroll
        for (int j = 0; j < 4; ++j) {
            int col = wave * 64 + j * 16 + lr;
            float bv = bias[col];
#pragma unroll
            for (int r = 0; r < 4; ++r) {
                int grow = rowBase + lg * 4 + r;
                float dg = degF[lg * 4 + r];
                Out[(size_t)grow * 256 + col] = f2bf(fmaxf(fmaf(dg, bv, acc[j][r]), 0.f));
            }
        }
    } else {
        __syncthreads();   // all As/Bs reads done before overwrite
        // out2 tile -> As (bf16), rows/cols disjoint per wave
#pragma unroll
        for (int j = 0; j < 4; ++j) {
            int col = wave * 64 + j * 16 + lr;
            float bv = bias[col];
#pragma unroll
            for (int r = 0; r < 4; ++r) {
                int rl = lg * 4 + r;
                As[rl * LDSA + col] = f2bf(fmaxf(fmaf(degF[rl], bv, acc[j][r]), 0.f));
            }
        }
        // stage W3 (40 n-rows x 256 k) into Bs[n*LDSA + k]
#pragma unroll
        for (int p = 0; p < 5; ++p) {
            int idx = p * 256 + tid;       // 0..1279
            int n = idx >> 5, c = (idx & 31) * 8;
            *(uint4*)(Bs + n * LDSA + c) = *(const uint4*)(W3b + (size_t)n * 256 + c);
        }
        __syncthreads();
        // gemm3: h3 = out2 @ W3 + b3 (waves 0..2 cover 48 cols, mask at 40)
        if (wave < 3) {
            f32x4 acc3 = {};
            for (int k0 = 0; k0 < 256; k0 += 32) {
                short8 af = *(const short8*)(As + lr * LDSA + k0 + lg * 8);
                short8 bf = *(const short8*)(Bs + (wave * 16 + lr) * LDSA + k0 + lg * 8);
                acc3 = __builtin_amdgcn_mfma_f32_16x16x32_bf16(af, bf, acc3, 0, 0, 0);
            }
            int col = wave * 16 + lr;
            if (col < N_CLASSES) {
                float bv = b3[col];
#pragma unroll
                for (int r = 0; r < 4; ++r) {
                    int grow = rowBase + lg * 4 + r;
                    Out[(size_t)grow * N_CLASSES + col] = f2bf(acc3[r] + bv);
                }
            }
        }
    }
}

// ---------------- agg40: out = relu(segsum(h3[src])) -> f32 ----------------
// One wave per node. 6 edges per load instr (10 lanes x 4 cols each, lanes
// 60-63 duplicate lane 0), 48-edge batches (CAP=96=2x48, dummy-padded), both
// batches' loads issued before any accumulation; 3-round shuffle fold.

__global__ __launch_bounds__(256)
void agg_relu_40_kernel(const ushort* __restrict__ h, const int* __restrict__ deg,
                        const int* __restrict__ esrc, float* __restrict__ out) {
    const int wv   = threadIdx.x >> 6;
    const int lane = threadIdx.x & 63;
    const int node = (blockIdx.x << 2) + wv;
    if (node >= N_NODES) return;
    int cnt = deg[node];
    if (cnt > CAP) cnt = CAP;
    const int* ep = esrc + node * CAP;
    const int l6  = (lane < 60) ? lane : 0;   // lanes 60-63: duplicate lane 0 (unused)
    const int g6  = l6 / 10;                  // edge group 0..5
    const int c10 = l6 - g6 * 10;             // col group 0..9 (cols 4*c10..+3)
    const int nb  = (cnt + 47) / 48;          // 0..2 batches of 48 edges

    uint2 v0[8], v1[8];
    if (nb > 0) {
#pragma unroll
        for (int u = 0; u < 8; ++u) {
            int s = ep[6 * u + g6];
            v0[u] = *(const uint2*)(h + (size_t)s * N_CLASSES + c10 * 4);
        }
    }
    if (nb > 1) {
#pragma unroll
        for (int u = 0; u < 8; ++u) {
            int s = ep[48 + 6 * u + g6];
            v1[u] = *(const uint2*)(h + (size_t)s * N_CLASSES + c10 * 4);
        }
    }
    float a0 = 0.f, a1 = 0.f, a2 = 0.f, a3 = 0.f;
    if (nb > 0) {
#pragma unroll
        for (int u = 0; u < 8; ++u) {
            a0 += bf2f((ushort)(v0[u].x & 0xffff)); a1 += bf2f((ushort)(v0[u].x >> 16));
            a2 += bf2f((ushort)(v0[u].y & 0xffff)); a3 += bf2f((ushort)(v0[u].y >> 16));
        }
    }
    if (nb > 1) {
#pragma unroll
        for (int u = 0; u < 8; ++u) {
            a0 += bf2f((ushort)(v1[u].x & 0xffff)); a1 += bf2f((ushort)(v1[u].x >> 16));
            a2 += bf2f((ushort)(v1[u].y & 0xffff)); a3 += bf2f((ushort)(v1[u].y >> 16));
        }
    }
    // fold 6 edge-groups down to group 0 (lanes 0..9): +30, then +10 and +20
#define FOLD40(x) { x += __shfl(x, lane + 30);                      \
                    float t1 = __shfl(x, lane + 10);                \
                    float t2 = __shfl(x, lane + 20);                \
                    x += t1 + t2; }
    FOLD40(a0); FOLD40(a1); FOLD40(a2); FOLD40(a3);
#undef FOLD40
    if (lane < 10) {
        float4 o;
        o.x = fmaxf(a0, 0.f); o.y = fmaxf(a1, 0.f);
        o.z = fmaxf(a2, 0.f); o.w = fmaxf(a3, 0.f);
        *(float4*)(out + (size_t)node * N_CLASSES + lane * 4) = o;
    }
}

// ---------------- launch ----------------

extern "C" void kernel_launch(void* const* d_in, const int* in_sizes, int n_in,
                              void* d_out, int out_size, void* d_ws, size_t ws_size,
                              hipStream_t stream) {
    const float* X     = (const float*)d_in[0];
    const int*   edges = (const int*)d_in[1];
    const float* W1 = (const float*)d_in[2];
    const float* b1 = (const float*)d_in[3];
    const float* W2 = (const float*)d_in[4];
    const float* b2 = (const float*)d_in[5];
    const float* W3 = (const float*)d_in[6];
    const float* b3 = (const float*)d_in[7];
    float* out = (float*)d_out;

    char* ws = (char*)d_ws;
    ushort* Xb   = (ushort*)(ws);                    //  5,120,512 B (10001 rows x 256)
    ushort* bufY = (ushort*)(ws + 5120512);          //  5,120,512 B (10001 rows)
    ushort* bufH = (ushort*)(ws + 10241024);         //    800,080 B (10001 rows x 40)
    ushort* W1b  = (ushort*)(ws + 11041104);         //    131,072 B (n-major)
    ushort* W2b  = (ushort*)(ws + 11172176);         //    131,072 B
    ushort* W3b  = (ushort*)(ws + 11303248);         //     20,480 B
    int*   cursor = (int*)(ws + 11323728);           //     40,000 B (== deg after place)
    int*   esrc   = (int*)(ws + 11363728);           //  3,840,000 B (10000 x 96)

    // 1: conversions + zero cursor + dummy-fill esrc + zero pad rows
    prep_kernel<<<512, 256, 0, stream>>>(X, W1, W2, W3, Xb, bufY, bufH,
                                         W1b, W2b, W3b, cursor, esrc);
    // 2: bucket-CSR place
    place_kernel<<<(N_EDGES + 255) / 256, 256, 0, stream>>>(edges, cursor, esrc);
    // 3: layer 1 fused (agg + GEMM + relu)
    layer_kernel<false><<<N_NODES / 16, 256, 0, stream>>>(
        Xb, W1b, b1, cursor, esrc, W3b, b3, bufY);
    // 4: layer 2 fused + chained layer-3 transform (h3 = out2@W3 + b3)
    layer_kernel<true><<<N_NODES / 16, 256, 0, stream>>>(
        bufY, W2b, b2, cursor, esrc, W3b, b3, bufH);
    // 5: final aggregation + relu -> d_out (f32)
    agg_relu_40_kernel<<<(N_NODES + 3) / 4, 256, 0, stream>>>(bufH, cursor, esrc, out);
}

// Round 3
// 160.507 us; speedup vs baseline: 1.3192x; 1.3192x over previous
//
#include <hip/hip_runtime.h>

// NodeClassifier 3-layer MP-GNN, MI355X. R9: TLP over ILP — split gather/GEMM.
// R8 post-mortem: pipelined in-kernel gather did NOT materialize (VGPR=92 <
// the ~100 the 2-deep pipeline needs -> compiler re-serialized it), and
// Occupancy=14% (625-block grid = 2.4 blocks/CU) left nothing to hide ~200-900
// cy gather latency. All pipes idle: VALU 13%, MFMA 1%, HBM 13%.
// Fix: node-parallel gather kernel (1 wave = 1 node, 2500 blocks, tiny LDS,
// ~40 waves/CU) so TLP hides latency; dense GEMM as its own 625-block kernel
// (proven 16x256 MFMA structure, As from global). +10 MB spill traffic/layer
// (trivial vs 164 MB gather). 7 dispatches:
//   prep, place, gather(Xb->G1), gemm1(G1->Y), gather(Y->G2),
//   gemm2+chain3(G2->H3), agg40(H3->out).
// agg(x@W+b) == agg(x)@W + deg*b. Lessons: grid.sync ~35us (R3); serial
// single-block straggler (R4); tile tweaks neutral (R7); source-level load
// pipelining defeated by compiler (R8).

#define N_NODES   10000
#define N_EDGES   320000
#define D_HID     256
#define N_CLASSES 40
#define CAP       96

typedef __attribute__((ext_vector_type(8))) short short8;
typedef __attribute__((ext_vector_type(4))) float f32x4;

__device__ __forceinline__ ushort f2bf(float f) {
    unsigned u = __float_as_uint(f);
    u = (u + 0x7fffu + ((u >> 16) & 1u)) >> 16;   // RNE; inputs finite
    return (ushort)u;
}
__device__ __forceinline__ float bf2f(ushort u) {
    return __uint_as_float(((unsigned)u) << 16);
}

// ---------------- prep: zero cursor, fill esrc with dummy, pad rows, bf16 conv ----------------

__global__ __launch_bounds__(256)
void prep_kernel(const float* __restrict__ X,
                 const float* __restrict__ W1, const float* __restrict__ W2,
                 const float* __restrict__ W3,
                 ushort* __restrict__ Xb, ushort* __restrict__ bufY,
                 ushort* __restrict__ bufH,
                 ushort* __restrict__ W1b, ushort* __restrict__ W2b,
                 ushort* __restrict__ W3b, int* __restrict__ cursor,
                 int* __restrict__ esrc) {
    const int tid  = blockIdx.x * 256 + threadIdx.x;
    const int nthr = gridDim.x * 256;
    for (int i = tid; i < N_NODES; i += nthr) cursor[i] = 0;
    // dummy-fill all bucket slots with padding node 10000 (zero row)
    for (int i = tid; i < N_NODES * CAP; i += nthr) esrc[i] = N_NODES;
    // zero the padding rows (gather2 reads bufY row 10000; agg40 reads bufH row 10000)
    ushort4 z; z.x = 0; z.y = 0; z.z = 0; z.w = 0;
    if (tid < 64) {
        ((ushort4*)Xb)[640000 + tid]   = z;   // row 10000 of Xb
        ((ushort4*)bufY)[640000 + tid] = z;   // row 10000 of bufY
    }
    if (tid < 10) ((ushort4*)bufH)[100000 + tid] = z;  // row 10000 of bufH
    // X -> bf16
    for (int i = tid; i < N_NODES * D_HID / 4; i += nthr) {
        float4 v = ((const float4*)X)[i];
        ushort4 o;
        o.x = f2bf(v.x); o.y = f2bf(v.y); o.z = f2bf(v.z); o.w = f2bf(v.w);
        ((ushort4*)Xb)[i] = o;
    }
    // weights -> bf16, transposed to n-major
    for (int i = tid; i < 141312; i += nthr) {
        if (i < 65536) {
            int n = i >> 8, k = i & 255;
            W1b[i] = f2bf(W1[k * 256 + n]);
        } else if (i < 131072) {
            int t2 = i - 65536;
            int n = t2 >> 8, k = t2 & 255;
            W2b[t2] = f2bf(W2[k * 256 + n]);
        } else {
            int t2 = i - 131072;
            int n = t2 >> 8, k = t2 & 255;
            W3b[t2] = f2bf(W3[k * N_CLASSES + n]);
        }
    }
}

// ---------------- place: bucket CSR via global atomics ----------------

__global__ __launch_bounds__(256)
void place_kernel(const int* __restrict__ edges, int* __restrict__ cursor,
                  int* __restrict__ esrc) {
    int e = blockIdx.x * 256 + threadIdx.x;
    if (e < N_EDGES) {
        int d = edges[N_EDGES + e];
        int pos = atomicAdd(&cursor[d], 1);
        if (pos < CAP) esrc[d * CAP + pos] = edges[e];
    }
}

// ---------------- gather: Ag[n] = sum_{e in bucket(n)} Xin[src(e)]  (bf16) ----------------
// 1 wave = 1 node, 4 waves/block, 2500 blocks (~10 blocks/CU queued -> high
// occupancy; ~60 VGPR, 1.6 KB LDS -> TLP hides the ~200-900 cy row-gather
// latency). Batch = 16 edges = 8 x uint4 loads (2 edges/instr: lanes 0-31 =
// edge 2u, lanes 32-63 = edge 2u+1). esrc dummy-padded -> no tail. Halves
// combined at the end via shfl_xor(32); lanes<32 store the bf16 row.

__global__ __launch_bounds__(256)
void gather_kernel(const ushort* __restrict__ Xin, const int* __restrict__ deg,
                   const int* __restrict__ esrc, ushort* __restrict__ Ag) {
    __shared__ int eidx[4 * CAP];     // 1536 B
    __shared__ int degL[4];

    const int tid  = threadIdx.x;
    const int w    = tid >> 6, lane = tid & 63;
    const int lo   = lane & 31, hi = lane >> 5;
    const int base = blockIdx.x * 4;

    for (int i = tid; i < 4 * CAP; i += 256) eidx[i] = esrc[base * CAP + i];
    if (tid < 4) {
        int c = deg[base + tid];
        degL[tid] = (c > CAP) ? CAP : c;
    }
    __syncthreads();

    const int node = base + w;
    const int nb   = (degL[w] + 15) >> 4;      // 0..6 batches of 16 edges
    const uint4* hp4 = (const uint4*)Xin;

    float a[8] = {};
    for (int b = 0; b < nb; ++b) {
        uint4 v[8];
#pragma unroll
        for (int u = 0; u < 8; ++u) {
            int e = eidx[w * CAP + b * 16 + 2 * u + hi];   // LDS broadcast x2
            v[u] = hp4[(size_t)e * 32 + lo];               // 16B/lane, 2 rows/instr
        }
#pragma unroll
        for (int u = 0; u < 8; ++u) {
            a[0] += bf2f((ushort)(v[u].x & 0xffff)); a[1] += bf2f((ushort)(v[u].x >> 16));
            a[2] += bf2f((ushort)(v[u].y & 0xffff)); a[3] += bf2f((ushort)(v[u].y >> 16));
            a[4] += bf2f((ushort)(v[u].z & 0xffff)); a[5] += bf2f((ushort)(v[u].z >> 16));
            a[6] += bf2f((ushort)(v[u].w & 0xffff)); a[7] += bf2f((ushort)(v[u].w >> 16));
        }
    }
#pragma unroll
    for (int j = 0; j < 8; ++j) a[j] += __shfl_xor(a[j], 32);
    if (lane < 32) {
        uint4 o;
        o.x = (unsigned)f2bf(a[0]) | ((unsigned)f2bf(a[1]) << 16);
        o.y = (unsigned)f2bf(a[2]) | ((unsigned)f2bf(a[3]) << 16);
        o.z = (unsigned)f2bf(a[4]) | ((unsigned)f2bf(a[5]) << 16);
        o.w = (unsigned)f2bf(a[6]) | ((unsigned)f2bf(a[7]) << 16);
        ((uint4*)(Ag + (size_t)node * 256))[lo] = o;       // zero-deg -> zero row
    }
}

// ---------------- gemm: Out = relu(Ag @ W + deg*b)  [+ chained @W3 + b3] ----------------
// Block: 16 rows x 256 cols, 4 waves, 625 blocks. As staged from global (8 KB),
// Bs staged per 32-k step (proven R7/R8 structure). CHAIN: out2 stays in LDS
// -> @W3 + b3 -> H3 (waves 0..2 cover 48 cols, mask at 40).

#define LDSA 264   // padded LDS row stride (bf16)

template<bool CHAIN>
__global__ __launch_bounds__(256)
void gemm_kernel(const ushort* __restrict__ Ag, const ushort* __restrict__ Bt,
                 const float* __restrict__ bias, const int* __restrict__ deg,
                 const ushort* __restrict__ W3b, const float* __restrict__ b3,
                 ushort* __restrict__ Out) {
    __shared__ ushort As[16 * LDSA];      // 8448 B; agg tile, reused as out2 when CHAIN
    __shared__ ushort Bs[40 * LDSA];      // 21120 B; main: [256 n][40-stride 32k]; chain: W3
    __shared__ float  degF[16];

    const int tid = threadIdx.x;
    const int wave = tid >> 6, lane = tid & 63;
    const int lr = lane & 15, lg = lane >> 4;
    const int rowBase = blockIdx.x * 16;

    // stage As tile: 16 rows x 32 uint4 chunks
#pragma unroll
    for (int p = 0; p < 2; ++p) {
        int idx = p * 256 + tid;          // 0..511
        int r = idx >> 5, c = idx & 31;
        *(uint4*)(As + r * LDSA + c * 8) =
            *(const uint4*)(Ag + (size_t)(rowBase + r) * 256 + c * 8);
    }
    if (tid < 16) degF[tid] = (float)deg[rowBase + tid];
    __syncthreads();

    f32x4 acc[4] = {};
    for (int k0 = 0; k0 < 256; k0 += 32) {
#pragma unroll
        for (int p = 0; p < 4; ++p) {
            int idx = p * 256 + tid;      // 1024 x 16B chunks
            int n = idx >> 2, c = (idx & 3) * 8;
            *(uint4*)(Bs + n * 40 + c) = *(const uint4*)(Bt + (size_t)n * 256 + k0 + c);
        }
        __syncthreads();                   // Bs ready
        short8 af = *(const short8*)(As + lr * LDSA + k0 + lg * 8);
#pragma unroll
        for (int j = 0; j < 4; ++j) {
            short8 bf = *(const short8*)(Bs + (wave * 64 + j * 16 + lr) * 40 + lg * 8);
            acc[j] = __builtin_amdgcn_mfma_f32_16x16x32_bf16(af, bf, acc[j], 0, 0, 0);
        }
        __syncthreads();                   // Bs reads done before next overwrite
    }

    if (!CHAIN) {
        // epilogue: relu(acc + deg*b) -> bf16 global (all rows exist: 625*16=10000)
#pragma unroll
        for (int j = 0; j < 4; ++j) {
            int col = wave * 64 + j * 16 + lr;
            float bv = bias[col];
#pragma unroll
            for (int r = 0; r < 4; ++r) {
                int grow = rowBase + lg * 4 + r;
                float dg = degF[lg * 4 + r];
                Out[(size_t)grow * 256 + col] = f2bf(fmaxf(fmaf(dg, bv, acc[j][r]), 0.f));
            }
        }
    } else {
        // out2 tile -> As (bf16), rows/cols disjoint per wave (loop's trailing
        // barrier guarantees all As/Bs reads are done)
#pragma unroll
        for (int j = 0; j < 4; ++j) {
            int col = wave * 64 + j * 16 + lr;
            float bv = bias[col];
#pragma unroll
            for (int r = 0; r < 4; ++r) {
                int rl = lg * 4 + r;
                As[rl * LDSA + col] = f2bf(fmaxf(fmaf(degF[rl], bv, acc[j][r]), 0.f));
            }
        }
        // stage W3 (40 n-rows x 256 k) into Bs[n*LDSA + k]
#pragma unroll
        for (int p = 0; p < 5; ++p) {
            int idx = p * 256 + tid;       // 0..1279
            int n = idx >> 5, c = (idx & 31) * 8;
            *(uint4*)(Bs + n * LDSA + c) = *(const uint4*)(W3b + (size_t)n * 256 + c);
        }
        __syncthreads();
        // gemm3: h3 = out2 @ W3 + b3 (waves 0..2 cover 48 cols, mask at 40)
        if (wave < 3) {
            f32x4 acc3 = {};
            for (int k0 = 0; k0 < 256; k0 += 32) {
                short8 af = *(const short8*)(As + lr * LDSA + k0 + lg * 8);
                short8 bf = *(const short8*)(Bs + (wave * 16 + lr) * LDSA + k0 + lg * 8);
                acc3 = __builtin_amdgcn_mfma_f32_16x16x32_bf16(af, bf, acc3, 0, 0, 0);
            }
            int col = wave * 16 + lr;
            if (col < N_CLASSES) {
                float bv = b3[col];
#pragma unroll
                for (int r = 0; r < 4; ++r) {
                    int grow = rowBase + lg * 4 + r;
                    Out[(size_t)grow * N_CLASSES + col] = f2bf(acc3[r] + bv);
                }
            }
        }
    }
}

// ---------------- agg40: out = relu(segsum(h3[src])) -> f32 ----------------
// One wave per node. 6 edges per load instr (10 lanes x 4 cols each, lanes
// 60-63 duplicate lane 0), 48-edge batches (CAP=96=2x48, dummy-padded), both
// batches' loads issued before any accumulation; 3-round shuffle fold.

__global__ __launch_bounds__(256)
void agg_relu_40_kernel(const ushort* __restrict__ h, const int* __restrict__ deg,
                        const int* __restrict__ esrc, float* __restrict__ out) {
    const int wv   = threadIdx.x >> 6;
    const int lane = threadIdx.x & 63;
    const int node = (blockIdx.x << 2) + wv;
    if (node >= N_NODES) return;
    int cnt = deg[node];
    if (cnt > CAP) cnt = CAP;
    const int* ep = esrc + node * CAP;
    const int l6  = (lane < 60) ? lane : 0;   // lanes 60-63: duplicate lane 0 (unused)
    const int g6  = l6 / 10;                  // edge group 0..5
    const int c10 = l6 - g6 * 10;             // col group 0..9 (cols 4*c10..+3)
    const int nb  = (cnt + 47) / 48;          // 0..2 batches of 48 edges

    uint2 v0[8], v1[8];
    if (nb > 0) {
#pragma unroll
        for (int u = 0; u < 8; ++u) {
            int s = ep[6 * u + g6];
            v0[u] = *(const uint2*)(h + (size_t)s * N_CLASSES + c10 * 4);
        }
    }
    if (nb > 1) {
#pragma unroll
        for (int u = 0; u < 8; ++u) {
            int s = ep[48 + 6 * u + g6];
            v1[u] = *(const uint2*)(h + (size_t)s * N_CLASSES + c10 * 4);
        }
    }
    float a0 = 0.f, a1 = 0.f, a2 = 0.f, a3 = 0.f;
    if (nb > 0) {
#pragma unroll
        for (int u = 0; u < 8; ++u) {
            a0 += bf2f((ushort)(v0[u].x & 0xffff)); a1 += bf2f((ushort)(v0[u].x >> 16));
            a2 += bf2f((ushort)(v0[u].y & 0xffff)); a3 += bf2f((ushort)(v0[u].y >> 16));
        }
    }
    if (nb > 1) {
#pragma unroll
        for (int u = 0; u < 8; ++u) {
            a0 += bf2f((ushort)(v1[u].x & 0xffff)); a1 += bf2f((ushort)(v1[u].x >> 16));
            a2 += bf2f((ushort)(v1[u].y & 0xffff)); a3 += bf2f((ushort)(v1[u].y >> 16));
        }
    }
    // fold 6 edge-groups down to group 0 (lanes 0..9): +30, then +10 and +20
#define FOLD40(x) { x += __shfl(x, lane + 30);                      \
                    float t1 = __shfl(x, lane + 10);                \
                    float t2 = __shfl(x, lane + 20);                \
                    x += t1 + t2; }
    FOLD40(a0); FOLD40(a1); FOLD40(a2); FOLD40(a3);
#undef FOLD40
    if (lane < 10) {
        float4 o;
        o.x = fmaxf(a0, 0.f); o.y = fmaxf(a1, 0.f);
        o.z = fmaxf(a2, 0.f); o.w = fmaxf(a3, 0.f);
        *(float4*)(out + (size_t)node * N_CLASSES + lane * 4) = o;
    }
}

// ---------------- launch ----------------

extern "C" void kernel_launch(void* const* d_in, const int* in_sizes, int n_in,
                              void* d_out, int out_size, void* d_ws, size_t ws_size,
                              hipStream_t stream) {
    const float* X     = (const float*)d_in[0];
    const int*   edges = (const int*)d_in[1];
    const float* W1 = (const float*)d_in[2];
    const float* b1 = (const float*)d_in[3];
    const float* W2 = (const float*)d_in[4];
    const float* b2 = (const float*)d_in[5];
    const float* W3 = (const float*)d_in[6];
    const float* b3 = (const float*)d_in[7];
    float* out = (float*)d_out;

    char* ws = (char*)d_ws;
    ushort* Xb   = (ushort*)(ws);                    //  5,120,512 B (10001 rows x 256)
    ushort* bufY = (ushort*)(ws + 5120512);          //  5,120,512 B (10001 rows)
    ushort* bufH = (ushort*)(ws + 10241024);         //    800,080 B (10001 rows x 40)
    ushort* W1b  = (ushort*)(ws + 11041104);         //    131,072 B (n-major)
    ushort* W2b  = (ushort*)(ws + 11172176);         //    131,072 B
    ushort* W3b  = (ushort*)(ws + 11303248);         //     20,480 B
    int*   cursor = (int*)(ws + 11323728);           //     40,000 B (== deg after place)
    int*   esrc   = (int*)(ws + 11363728);           //  3,840,000 B (10000 x 96)
    ushort* G1   = (ushort*)(ws + 15203728);         //  5,120,000 B (10000 rows x 256)
    ushort* G2   = (ushort*)(ws + 20323728);         //  5,120,000 B

    // 1: conversions + zero cursor + dummy-fill esrc + zero pad rows
    prep_kernel<<<512, 256, 0, stream>>>(X, W1, W2, W3, Xb, bufY, bufH,
                                         W1b, W2b, W3b, cursor, esrc);
    // 2: bucket-CSR place
    place_kernel<<<(N_EDGES + 255) / 256, 256, 0, stream>>>(edges, cursor, esrc);
    // 3: gather layer-1 input aggregation (node-parallel, high TLP)
    gather_kernel<<<N_NODES / 4, 256, 0, stream>>>(Xb, cursor, esrc, G1);
    // 4: layer-1 transform: bufY = relu(G1@W1 + deg*b1)
    gemm_kernel<false><<<N_NODES / 16, 256, 0, stream>>>(
        G1, W1b, b1, cursor, W3b, b3, bufY);
    // 5: gather layer-2 aggregation
    gather_kernel<<<N_NODES / 4, 256, 0, stream>>>(bufY, cursor, esrc, G2);
    // 6: layer-2 transform + chained layer-3 transform -> bufH
    gemm_kernel<true><<<N_NODES / 16, 256, 0, stream>>>(
        G2, W2b, b2, cursor, W3b, b3, bufH);
    // 7: final aggregation + relu -> d_out (f32)
    agg_relu_40_kernel<<<(N_NODES + 3) / 4, 256, 0, stream>>>(bufH, cursor, esrc, out);
}